// Round 6
// baseline (82285.541 us; speedup 1.0000x reference)
//
#include <hip/hip_runtime.h>

#define B_ 64
#define T_ 512
#define IN0_ 512
#define H_ 1024
#define C_ 1000
#define NWG 256
#define NTHR 256

typedef _Float16 f16;
typedef _Float16 f16x8 __attribute__((ext_vector_type(8)));
typedef _Float16 f16x4 __attribute__((ext_vector_type(4)));
typedef float f32x4 __attribute__((ext_vector_type(4)));

struct Args {
  const float* x;
  const float* Wih[4];
  const float* Whh[4];
  const float* bih[4];
  const float* bhh[4];
  const float* fcw;
  const float* fcb;
  float* out;
  f16* wpack;
  f16* x16;
  f16* houts;   // [4 layers][2 parity][64][1024] f16
  float* h32;   // [4 layers][64][1024] f32 master hidden
  int* bar;     // [0]=count, [1]=generation
};

__device__ __forceinline__ float sigmoid_f(float x) {
  return 1.0f / (1.0f + __expf(-x));
}
__device__ __forceinline__ float tanh_f(float x) {
  return 1.0f - 2.0f / (__expf(2.0f * x) + 1.0f);
}

// ROUND-1 VERBATIM barrier (HW-verified PASS): count+generation, ACQ_REL
// fetch_add arrival, per-poll ACQUIRE spin, __threadfence() executed by ALL
// threads on BOTH sides.
__device__ __forceinline__ void grid_barrier(int* bar) {
  __threadfence();     // release: drain + make my stores device-visible
  __syncthreads();     // all threads of this WG have fenced
  if (threadIdx.x == 0) {
    int* cnt = bar;
    int* gen = bar + 1;
    int g = __hip_atomic_load(gen, __ATOMIC_RELAXED, __HIP_MEMORY_SCOPE_AGENT);
    int v = __hip_atomic_fetch_add(cnt, 1, __ATOMIC_ACQ_REL, __HIP_MEMORY_SCOPE_AGENT);
    if (v == NWG - 1) {
      __hip_atomic_store(cnt, 0, __ATOMIC_RELAXED, __HIP_MEMORY_SCOPE_AGENT);
      __hip_atomic_store(gen, g + 1, __ATOMIC_RELEASE, __HIP_MEMORY_SCOPE_AGENT);
    } else {
      int cur;
      do {
        __builtin_amdgcn_s_sleep(2);
        cur = __hip_atomic_load(gen, __ATOMIC_ACQUIRE, __HIP_MEMORY_SCOPE_AGENT);
      } while (cur == g);
    }
  }
  __syncthreads();
  __threadfence();     // acquire: invalidate stale cached lines before reads
}

// Packed-weight layer offsets in f16 elements.
// layer0: 3072*1536 = 4718592 ; layers1..3: 3072*2048 = 6291456 each.
__constant__ __device__ const size_t WOFF_[4] = {0ul, 4718592ul, 11010048ul, 17301504ul};

// ROUND-1 VERBATIM hot loop; the ONLY change is IN as a template constant so
// NKB/NXB are constexpr and the k-loops fully unroll (deep load pipelining).
// No index expression differs from the round-1 PASS kernel.
template <int IN>
__device__ void phase1(const Args& a, int layer, int sub) {
  constexpr int NKB = (IN + H_) / 32;   // 48 (layer0) or 64
  constexpr int NXB = IN / 32;          // 16 or 32

  const int tid = threadIdx.x;
  const int wave = tid >> 6;
  const int lane = tid & 63;
  const int jc = lane & 15;
  const int j = sub * 16 + jc;     // hidden unit (B/C column)
  const int kg = lane >> 4;        // k-group within fragment
  const int arow = wave * 16 + jc; // batch row this lane loads for A

  const float bir  = a.bih[layer][j];
  const float bhr  = a.bhh[layer][j];
  const float biz  = a.bih[layer][H_ + j];
  const float bhz  = a.bhh[layer][H_ + j];
  const float bin_ = a.bih[layer][2 * H_ + j];
  const float bhn  = a.bhh[layer][2 * H_ + j];

  const f16x8* wpr = (const f16x8*)(a.wpack + WOFF_[layer] + (size_t)sub * 3 * NKB * 512) + lane;
  const f16x8* wpz = wpr + (size_t)NKB * 64;
  const f16x8* wpn = wpz + (size_t)NKB * 64;

  float* h32l = a.h32 + (size_t)layer * B_ * H_;
  f16* hout[2] = { a.houts + (size_t)(layer * 2 + 0) * B_ * H_,
                   a.houts + (size_t)(layer * 2 + 1) * B_ * H_ };
  const f16* xprev[2] = {
    layer ? a.houts + (size_t)((layer - 1) * 2 + 0) * B_ * H_ : (const f16*)nullptr,
    layer ? a.houts + (size_t)((layer - 1) * 2 + 1) * B_ * H_ : (const f16*)nullptr };

  for (int u = 0; u < T_ + 3; ++u) {
    const int t = u - layer;
    if (t >= 0 && t < T_) {
      f32x4 accR  = {0, 0, 0, 0};
      f32x4 accZ  = {0, 0, 0, 0};
      f32x4 accNX = {0, 0, 0, 0};
      f32x4 accNH = {0, 0, 0, 0};
      const f16* xs = (IN == IN0_)
          ? a.x16 + ((size_t)t * B_ + arow) * IN0_ + kg * 8
          : xprev[t & 1] + (size_t)arow * H_ + kg * 8;
      const f16* hs = hout[(t + 1) & 1] + (size_t)arow * H_ + kg * 8;

#pragma unroll
      for (int kb = 0; kb < NXB; ++kb) {           // x part of K
        f16x8 af = *(const f16x8*)(xs + kb * 32);
        f16x8 br = wpr[kb * 64];
        f16x8 bz = wpz[kb * 64];
        f16x8 bn = wpn[kb * 64];
        accR  = __builtin_amdgcn_mfma_f32_16x16x32_f16(af, br, accR, 0, 0, 0);
        accZ  = __builtin_amdgcn_mfma_f32_16x16x32_f16(af, bz, accZ, 0, 0, 0);
        accNX = __builtin_amdgcn_mfma_f32_16x16x32_f16(af, bn, accNX, 0, 0, 0);
      }
#pragma unroll
      for (int kb = NXB; kb < NKB; ++kb) {         // h part of K
        f16x8 af = *(const f16x8*)(hs + (kb - NXB) * 32);
        f16x8 br = wpr[kb * 64];
        f16x8 bz = wpz[kb * 64];
        f16x8 bn = wpn[kb * 64];
        accR  = __builtin_amdgcn_mfma_f32_16x16x32_f16(af, br, accR, 0, 0, 0);
        accZ  = __builtin_amdgcn_mfma_f32_16x16x32_f16(af, bz, accZ, 0, 0, 0);
        accNH = __builtin_amdgcn_mfma_f32_16x16x32_f16(af, bn, accNH, 0, 0, 0);
      }

      f16* ho = hout[t & 1];
#pragma unroll
      for (int i = 0; i < 4; ++i) {
        const int b = wave * 16 + kg * 4 + i;      // C row -> batch
        const float r = sigmoid_f(accR[i] + bir + bhr);
        const float zz = sigmoid_f(accZ[i] + biz + bhz);
        const float nn = tanh_f(accNX[i] + bin_ + r * (accNH[i] + bhn));
        const float hp = h32l[(size_t)b * H_ + j];
        const float hnew = (1.0f - zz) * nn + zz * hp;
        h32l[(size_t)b * H_ + j] = hnew;
        ho[(size_t)b * H_ + j] = (f16)hnew;
      }
    }
    grid_barrier(a.bar);
  }
}

__global__ void __launch_bounds__(NTHR, 1) gru_pipeline(Args a) {
  const int tid = threadIdx.x;
  const int gtid = blockIdx.x * NTHR + tid;
  const int NT = NWG * NTHR;

  // ================= Phase 0: prologue (every call, deterministic) ========
  // 0a. x -> fp16, transposed to [t][b][512].
  {
    const int nf4 = B_ * T_ * IN0_ / 4;
    for (int i = gtid; i < nf4; i += NT) {
      int k4 = i & 127;       // 512/4
      int q = i >> 7;
      int b = q & 63;
      int t = q >> 6;
      const float4 v = *(const float4*)(a.x + ((size_t)b * T_ + t) * IN0_ + k4 * 4);
      f16x4 o;
      o[0] = (f16)v.x; o[1] = (f16)v.y; o[2] = (f16)v.z; o[3] = (f16)v.w;
      *(f16x4*)(a.x16 + (size_t)i * 4) = o;
    }
  }
  // 0b. zero hidden-state buffers (ws is poisoned 0xAA; h0 must be 0).
  {
    f16x8 z8 = {0, 0, 0, 0, 0, 0, 0, 0};
    for (int i = gtid; i < 4 * 2 * B_ * H_ / 8; i += NT)
      ((f16x8*)a.houts)[i] = z8;
    f32x4 z4 = {0, 0, 0, 0};
    for (int i = gtid; i < 4 * B_ * H_ / 4; i += NT)
      ((f32x4*)a.h32)[i] = z4;
  }
  // 0c. repack weights into MFMA B-fragment order (fp16). ROUND-1 VERBATIM.
  for (int l = 0; l < 4; ++l) {
    const int In = l ? H_ : IN0_;
    const int K = In + H_;
    const int NKB = K / 32;
    const float* Wih = a.Wih[l];
    const float* Whh = a.Whh[l];
    f16* wp = a.wpack + WOFF_[l];
    const int nunits = 3 * H_ * K / 8;
    for (int uu = gtid; uu < nunits; uu += NT) {
      int lane = uu & 63;
      int q = uu >> 6;
      int kb = q % NKB; q /= NKB;
      int gate = q % 3;
      int subb = q / 3;
      int j = subb * 16 + (lane & 15);
      int g = gate * H_ + j;
      int k = kb * 32 + (lane >> 4) * 8;
      const float* src = (k < In) ? (Wih + (size_t)g * In + k)
                                  : (Whh + (size_t)g * H_ + (k - In));
      f16x8 vv;
#pragma unroll
      for (int e = 0; e < 8; ++e) vv[e] = (f16)src[e];
      ((f16x8*)wp)[uu] = vv;
    }
  }

  grid_barrier(a.bar);

  // ================= Phase 1: pipelined recurrence ========================
  const int wg = blockIdx.x;
  const int layer = wg >> 6;      // 64 WGs per layer
  const int sub = wg & 63;        // owns hidden units [sub*16, sub*16+16)

  if (layer == 0) phase1<IN0_>(a, layer, sub);
  else            phase1<H_>(a, layer, sub);

  // ================= Phase 2: final FC [64,1024]x[1024,1000] =============
  for (int o = gtid; o < B_ * C_; o += NT) {
    const int b = o / C_;
    const int c = o - b * C_;
    const float* hv = a.h32 + (size_t)3 * B_ * H_ + (size_t)b * H_;
    const float* wv = a.fcw + (size_t)c * H_;
    float s = a.fcb[c];
    for (int k = 0; k < H_; k += 4) {
      const float4 h4 = *(const float4*)(hv + k);
      const float4 w4 = *(const float4*)(wv + k);
      s = fmaf(h4.x, w4.x, s);
      s = fmaf(h4.y, w4.y, s);
      s = fmaf(h4.z, w4.z, s);
      s = fmaf(h4.w, w4.w, s);
    }
    a.out[o] = s;
  }
}

extern "C" void kernel_launch(void* const* d_in, const int* in_sizes, int n_in,
                              void* d_out, int out_size, void* d_ws, size_t ws_size,
                              hipStream_t stream) {
  Args a;
  a.x = (const float*)d_in[0];
  for (int l = 0; l < 4; ++l) {
    a.Wih[l] = (const float*)d_in[1 + 4 * l];
    a.Whh[l] = (const float*)d_in[2 + 4 * l];
    a.bih[l] = (const float*)d_in[3 + 4 * l];
    a.bhh[l] = (const float*)d_in[4 + 4 * l];
  }
  a.fcw = (const float*)d_in[17];
  a.fcb = (const float*)d_in[18];
  a.out = (float*)d_out;

  char* ws = (char*)d_ws;
  size_t off = 0;
  a.wpack = (f16*)(ws + off); off += 23592960ul * 2;   // 47185920 B
  a.x16   = (f16*)(ws + off); off += 16777216ul * 2;   // 33554432 B
  a.houts = (f16*)(ws + off); off += 4ul * 2 * B_ * H_ * 2;   // 1 MiB
  a.h32   = (float*)(ws + off); off += 4ul * B_ * H_ * 4;     // 1 MiB
  a.bar   = (int*)(ws + off); off += 256;

  hipMemsetAsync(a.bar, 0, 2 * sizeof(int), stream);

  void* params[] = { &a };
  hipError_t err = hipLaunchCooperativeKernel((void*)gru_pipeline, dim3(NWG),
                                              dim3(NTHR), params, 0, stream);
  if (err != hipSuccess) {
    // Fallback: plain launch. 256 WGs at 1 WG/CU are co-resident in practice;
    // barrier logic identical.
    gru_pipeline<<<dim3(NWG), dim3(NTHR), 0, stream>>>(a);
  }
}

// Round 8
// 46076.144 us; speedup vs baseline: 1.7859x; 1.7859x over previous
//
#include <hip/hip_runtime.h>

#define B_ 64
#define T_ 512
#define IN0_ 512
#define H_ 1024
#define C_ 1000
#define NWG 256
#define NTHR 256

typedef _Float16 f16;
typedef _Float16 f16x8 __attribute__((ext_vector_type(8)));
typedef _Float16 f16x4 __attribute__((ext_vector_type(4)));
typedef float f32x4 __attribute__((ext_vector_type(4)));

struct Args {
  const float* x;
  const float* Wih[4];
  const float* Whh[4];
  const float* bih[4];
  const float* bhh[4];
  const float* fcw;
  const float* fcb;
  float* out;
  f16* wpack;
  f16* x16;
  f16* houts;   // [4 layers][2 parity][64][1024] f16
  float* h32;   // [4 layers][64][1024] f32 master hidden (thread-private RMW)
  int* flags;   // NWG padded flags; flags[NWG*32] = go word (light barrier)
  int* bar;     // [0]=count, [1]=generation (heavy barrier)
};

__device__ __forceinline__ float sigmoid_f(float x) {
  return 1.0f / (1.0f + __expf(-x));
}
__device__ __forceinline__ float tanh_f(float x) {
  return 1.0f - 2.0f / (__expf(2.0f * x) + 1.0f);
}

// HEAVY barrier — ROUND-1 VERBATIM (HW-verified). Full agent fences both
// sides. Used only twice (post-prologue, pre-FC).
__device__ __forceinline__ void heavy_barrier(int* bar) {
  __threadfence();
  __syncthreads();
  if (threadIdx.x == 0) {
    int* cnt = bar;
    int* gen = bar + 1;
    int g = __hip_atomic_load(gen, __ATOMIC_RELAXED, __HIP_MEMORY_SCOPE_AGENT);
    int v = __hip_atomic_fetch_add(cnt, 1, __ATOMIC_ACQ_REL, __HIP_MEMORY_SCOPE_AGENT);
    if (v == NWG - 1) {
      __hip_atomic_store(cnt, 0, __ATOMIC_RELAXED, __HIP_MEMORY_SCOPE_AGENT);
      __hip_atomic_store(gen, g + 1, __ATOMIC_RELEASE, __HIP_MEMORY_SCOPE_AGENT);
    } else {
      int cur;
      do {
        __builtin_amdgcn_s_sleep(2);
        cur = __hip_atomic_load(gen, __ATOMIC_ACQUIRE, __HIP_MEMORY_SCOPE_AGENT);
      } while (cur == g);
    }
  }
  __syncthreads();
  __threadfence();
}

// LIGHT per-step barrier — NO acquire fence (keeps L1/L2 warm for weights).
// Release side: all threads fence(release,agent) = waitcnt + wbl2, pushing
// this step's ho/h32 stores to the memory-side (always-coherent) L3. Flag
// and go use relaxed sc1 ops; consumers re-read shared data via agent-scope
// atomic loads that are served at L3, so no cache invalidate is needed.
__device__ __forceinline__ void light_barrier(int* flags, int step) {
  int* go = flags + NWG * 32;
  __builtin_amdgcn_fence(__ATOMIC_RELEASE, "agent");
  __syncthreads();
  if (blockIdx.x == 0) {
    const int t = threadIdx.x;
    if (t > 0) {                   // thread t monitors WG t; WG0 implicit
      while (__hip_atomic_load(flags + t * 32, __ATOMIC_RELAXED,
                               __HIP_MEMORY_SCOPE_AGENT) < step)
        __builtin_amdgcn_s_sleep(1);
    }
    __syncthreads();
    if (t == 0)
      __hip_atomic_store(go, step, __ATOMIC_RELAXED, __HIP_MEMORY_SCOPE_AGENT);
  } else {
    if (threadIdx.x == 0) {
      __hip_atomic_store(flags + blockIdx.x * 32, step, __ATOMIC_RELAXED,
                         __HIP_MEMORY_SCOPE_AGENT);
      while (__hip_atomic_load(go, __ATOMIC_RELAXED,
                               __HIP_MEMORY_SCOPE_AGENT) < step)
        __builtin_amdgcn_s_sleep(1);
    }
  }
  __syncthreads();
}

// Coherent 16B fragment load: two relaxed agent-scope 8B atomic loads.
// Agent scope -> sc1 -> bypasses (possibly stale) L1/per-XCD-L2, served at
// the memory-side L3 where producers' wbl2 already deposited the data.
union U16B { unsigned long long u[2]; f16x8 v; };
__device__ __forceinline__ f16x8 aload16(const f16* p) {
  unsigned long long* q = (unsigned long long*)p;
  U16B r;
  r.u[0] = __hip_atomic_load(q,     __ATOMIC_RELAXED, __HIP_MEMORY_SCOPE_AGENT);
  r.u[1] = __hip_atomic_load(q + 1, __ATOMIC_RELAXED, __HIP_MEMORY_SCOPE_AGENT);
  return r.v;
}

// Packed-weight layer offsets in f16 elements.
__constant__ __device__ const size_t WOFF_[4] = {0ul, 4718592ul, 11010048ul, 17301504ul};

// R6-VERIFIED hot loop. Only change: h fragments (and xprev for layers>=1)
// load via aload16 (coherent); weights/x16 stay ordinary cached loads.
template <int IN, bool XA>
__device__ void phase1(const Args& a, int layer, int sub) {
  constexpr int NKB = (IN + H_) / 32;   // 48 (layer0) or 64
  constexpr int NXB = IN / 32;          // 16 or 32

  const int tid = threadIdx.x;
  const int wave = tid >> 6;
  const int lane = tid & 63;
  const int jc = lane & 15;
  const int j = sub * 16 + jc;     // hidden unit (B/C column)
  const int kg = lane >> 4;        // k-group within fragment
  const int arow = wave * 16 + jc; // batch row this lane loads for A

  const float bir  = a.bih[layer][j];
  const float bhr  = a.bhh[layer][j];
  const float biz  = a.bih[layer][H_ + j];
  const float bhz  = a.bhh[layer][H_ + j];
  const float bin_ = a.bih[layer][2 * H_ + j];
  const float bhn  = a.bhh[layer][2 * H_ + j];

  const f16x8* wpr = (const f16x8*)(a.wpack + WOFF_[layer] + (size_t)sub * 3 * NKB * 512) + lane;
  const f16x8* wpz = wpr + (size_t)NKB * 64;
  const f16x8* wpn = wpz + (size_t)NKB * 64;

  float* h32l = a.h32 + (size_t)layer * B_ * H_;
  f16* hout[2] = { a.houts + (size_t)(layer * 2 + 0) * B_ * H_,
                   a.houts + (size_t)(layer * 2 + 1) * B_ * H_ };
  const f16* xprev[2] = {
    layer ? a.houts + (size_t)((layer - 1) * 2 + 0) * B_ * H_ : (const f16*)nullptr,
    layer ? a.houts + (size_t)((layer - 1) * 2 + 1) * B_ * H_ : (const f16*)nullptr };

  for (int u = 0; u < T_ + 3; ++u) {
    const int t = u - layer;
    if (t >= 0 && t < T_) {
      f32x4 accR  = {0, 0, 0, 0};
      f32x4 accZ  = {0, 0, 0, 0};
      f32x4 accNX = {0, 0, 0, 0};
      f32x4 accNH = {0, 0, 0, 0};
      const f16* xs = (IN == IN0_)
          ? a.x16 + ((size_t)t * B_ + arow) * IN0_ + kg * 8
          : xprev[t & 1] + (size_t)arow * H_ + kg * 8;
      const f16* hs = hout[(t + 1) & 1] + (size_t)arow * H_ + kg * 8;

#pragma unroll
      for (int kb = 0; kb < NXB; ++kb) {           // x part of K
        f16x8 af;
        if constexpr (XA) af = aload16(xs + kb * 32);
        else              af = *(const f16x8*)(xs + kb * 32);
        f16x8 br = wpr[kb * 64];
        f16x8 bz = wpz[kb * 64];
        f16x8 bn = wpn[kb * 64];
        accR  = __builtin_amdgcn_mfma_f32_16x16x32_f16(af, br, accR, 0, 0, 0);
        accZ  = __builtin_amdgcn_mfma_f32_16x16x32_f16(af, bz, accZ, 0, 0, 0);
        accNX = __builtin_amdgcn_mfma_f32_16x16x32_f16(af, bn, accNX, 0, 0, 0);
      }
#pragma unroll
      for (int kb = NXB; kb < NKB; ++kb) {         // h part of K (coherent)
        f16x8 af = aload16(hs + (kb - NXB) * 32);
        f16x8 br = wpr[kb * 64];
        f16x8 bz = wpz[kb * 64];
        f16x8 bn = wpn[kb * 64];
        accR  = __builtin_amdgcn_mfma_f32_16x16x32_f16(af, br, accR, 0, 0, 0);
        accZ  = __builtin_amdgcn_mfma_f32_16x16x32_f16(af, bz, accZ, 0, 0, 0);
        accNH = __builtin_amdgcn_mfma_f32_16x16x32_f16(af, bn, accNH, 0, 0, 0);
      }

      f16* ho = hout[t & 1];
#pragma unroll
      for (int i = 0; i < 4; ++i) {
        const int b = wave * 16 + kg * 4 + i;      // C row -> batch
        const float r = sigmoid_f(accR[i] + bir + bhr);
        const float zz = sigmoid_f(accZ[i] + biz + bhz);
        const float nn = tanh_f(accNX[i] + bin_ + r * (accNH[i] + bhn));
        const float hp = h32l[(size_t)b * H_ + j];
        const float hnew = (1.0f - zz) * nn + zz * hp;
        h32l[(size_t)b * H_ + j] = hnew;
        ho[(size_t)b * H_ + j] = (f16)hnew;
      }
    }
    light_barrier(a.flags, u + 1);
  }
}

__global__ void __launch_bounds__(NTHR, 1) gru_pipeline(Args a) {
  const int tid = threadIdx.x;
  const int gtid = blockIdx.x * NTHR + tid;
  const int NT = NWG * NTHR;

  // ================= Phase 0: prologue (R6 verbatim) ======================
  // 0a. x -> fp16, transposed to [t][b][512].
  {
    const int nf4 = B_ * T_ * IN0_ / 4;
    for (int i = gtid; i < nf4; i += NT) {
      int k4 = i & 127;       // 512/4
      int q = i >> 7;
      int b = q & 63;
      int t = q >> 6;
      const float4 v = *(const float4*)(a.x + ((size_t)b * T_ + t) * IN0_ + k4 * 4);
      f16x4 o;
      o[0] = (f16)v.x; o[1] = (f16)v.y; o[2] = (f16)v.z; o[3] = (f16)v.w;
      *(f16x4*)(a.x16 + (size_t)i * 4) = o;
    }
  }
  // 0b. zero hidden-state buffers (ws is poisoned 0xAA; h0 must be 0).
  {
    f16x8 z8 = {0, 0, 0, 0, 0, 0, 0, 0};
    for (int i = gtid; i < 4 * 2 * B_ * H_ / 8; i += NT)
      ((f16x8*)a.houts)[i] = z8;
    f32x4 z4 = {0, 0, 0, 0};
    for (int i = gtid; i < 4 * B_ * H_ / 4; i += NT)
      ((f32x4*)a.h32)[i] = z4;
  }
  // 0c. repack weights into MFMA B-fragment order (R6 verbatim, verified).
  for (int l = 0; l < 4; ++l) {
    const int In = l ? H_ : IN0_;
    const int K = In + H_;
    const int NKB = K / 32;
    const float* Wih = a.Wih[l];
    const float* Whh = a.Whh[l];
    f16* wp = a.wpack + WOFF_[l];
    const int nunits = 3 * H_ * K / 8;
    for (int uu = gtid; uu < nunits; uu += NT) {
      int lane = uu & 63;
      int q = uu >> 6;
      int kb = q % NKB; q /= NKB;
      int gate = q % 3;
      int subb = q / 3;
      int j = subb * 16 + (lane & 15);
      int g = gate * H_ + j;
      int k = kb * 32 + (lane >> 4) * 8;
      const float* src = (k < In) ? (Wih + (size_t)g * In + k)
                                  : (Whh + (size_t)g * H_ + (k - In));
      f16x8 vv;
#pragma unroll
      for (int e = 0; e < 8; ++e) vv[e] = (f16)src[e];
      ((f16x8*)wp)[uu] = vv;
    }
  }

  heavy_barrier(a.bar);   // full flush+invalidate once: x16/wpack now stable

  // ================= Phase 1: pipelined recurrence ========================
  const int wg = blockIdx.x;
  const int layer = wg >> 6;      // 64 WGs per layer
  const int sub = wg & 63;        // owns hidden units [sub*16, sub*16+16)

  if (layer == 0) phase1<IN0_, false>(a, layer, sub);
  else            phase1<H_, true>(a, layer, sub);

  heavy_barrier(a.bar);   // full visibility for h32 before FC

  // ================= Phase 2: final FC [64,1024]x[1024,1000] =============
  for (int o = gtid; o < B_ * C_; o += NT) {
    const int b = o / C_;
    const int c = o - b * C_;
    const float* hv = a.h32 + (size_t)3 * B_ * H_ + (size_t)b * H_;
    const float* wv = a.fcw + (size_t)c * H_;
    float s = a.fcb[c];
    for (int k = 0; k < H_; k += 4) {
      const float4 h4 = *(const float4*)(hv + k);
      const float4 w4 = *(const float4*)(wv + k);
      s = fmaf(h4.x, w4.x, s);
      s = fmaf(h4.y, w4.y, s);
      s = fmaf(h4.z, w4.z, s);
      s = fmaf(h4.w, w4.w, s);
    }
    a.out[o] = s;
  }
}

extern "C" void kernel_launch(void* const* d_in, const int* in_sizes, int n_in,
                              void* d_out, int out_size, void* d_ws, size_t ws_size,
                              hipStream_t stream) {
  Args a;
  a.x = (const float*)d_in[0];
  for (int l = 0; l < 4; ++l) {
    a.Wih[l] = (const float*)d_in[1 + 4 * l];
    a.Whh[l] = (const float*)d_in[2 + 4 * l];
    a.bih[l] = (const float*)d_in[3 + 4 * l];
    a.bhh[l] = (const float*)d_in[4 + 4 * l];
  }
  a.fcw = (const float*)d_in[17];
  a.fcb = (const float*)d_in[18];
  a.out = (float*)d_out;

  char* ws = (char*)d_ws;
  size_t off = 0;
  a.wpack = (f16*)(ws + off); off += 23592960ul * 2;                  // 45 MiB
  a.x16   = (f16*)(ws + off); off += 16777216ul * 2;                  // 32 MiB
  a.houts = (f16*)(ws + off); off += 4ul * 2 * B_ * H_ * 2;           // 1 MiB
  a.h32   = (float*)(ws + off); off += 4ul * B_ * H_ * 4;             // 1 MiB
  a.flags = (int*)(ws + off); off += (NWG * 32 + 32) * sizeof(int);   // 33 KiB
  a.bar   = (int*)(ws + off); off += 256;

  hipMemsetAsync(a.flags, 0, (NWG * 32 + 32) * sizeof(int) + 256, stream);

  void* params[] = { &a };
  hipError_t err = hipLaunchCooperativeKernel((void*)gru_pipeline, dim3(NWG),
                                              dim3(NTHR), params, 0, stream);
  if (err != hipSuccess) {
    gru_pipeline<<<dim3(NWG), dim3(NTHR), 0, stream>>>(a);
  }
}